// Round 3
// baseline (465.211 us; speedup 1.0000x reference)
//
#include <hip/hip_runtime.h>

#define N_NODES 100000
#define N_EDGES 600000
#define NF 128
#define NG 256

typedef _Float16 f16;
typedef f16 half8 __attribute__((ext_vector_type(8)));
typedef f16 half4v __attribute__((ext_vector_type(4)));
typedef float float4v __attribute__((ext_vector_type(4)));

// ---------------- preprocessing: degrees, dinv, CSR ----------------

__global__ void k_count(const int* __restrict__ ei, int* __restrict__ counts) {
    int e = blockIdx.x * 256 + threadIdx.x;
    if (e < N_EDGES) atomicAdd(&counts[ei[N_EDGES + e]], 1);
}

__global__ void k_scan1(const int* __restrict__ counts, int* __restrict__ row_ptr,
                        int* __restrict__ bsums, float* __restrict__ dinv) {
    __shared__ int s[256];
    int b = blockIdx.x, t = threadIdx.x;
    int base = b * 2048 + t * 8;
    int local[8];
    int sum = 0;
#pragma unroll
    for (int q = 0; q < 8; q++) {
        int idx = base + q;
        int v = (idx < N_NODES) ? counts[idx] : 0;
        if (idx < N_NODES) dinv[idx] = 1.0f / sqrtf((float)(v + 1));
        local[q] = sum;
        sum += v;
    }
    s[t] = sum;
    __syncthreads();
    for (int off = 1; off < 256; off <<= 1) {
        int v = 0;
        if (t >= off) v = s[t - off];
        __syncthreads();
        s[t] += v;
        __syncthreads();
    }
    int excl = s[t] - sum;
#pragma unroll
    for (int q = 0; q < 8; q++) {
        int idx = base + q;
        if (idx < N_NODES) row_ptr[idx] = excl + local[q];
    }
    if (t == 255) bsums[b] = s[255];   // raw per-block sums (prefixed in scan3)
}

// scan3 folds the bsums prefix (2048-node group per 8 blocks of 256)
__global__ void k_scan3(int* __restrict__ row_ptr, const int* __restrict__ bsums,
                        int* __restrict__ cursor) {
    __shared__ int pre;
    if (threadIdx.x == 0) {
        int g = blockIdx.x >> 3;
        int s = 0;
        for (int j = 0; j < g; j++) s += bsums[j];
        pre = s;
    }
    __syncthreads();
    int i = blockIdx.x * 256 + threadIdx.x;
    if (i < N_NODES) {
        int v = row_ptr[i] + pre;
        row_ptr[i] = v;
        cursor[i] = v;
        if (i == 0) row_ptr[N_NODES] = N_EDGES;
    }
}

// fill CSR col[]; first 256 blocks also do wprep in FRAGMENT ORDER (R11-proven).
__global__ void k_fill(const int* __restrict__ ei, int* __restrict__ cursor,
                       int* __restrict__ col,
                       const float* __restrict__ W1, const float* __restrict__ W2,
                       const float* __restrict__ W3, const float* __restrict__ W4,
                       f16* __restrict__ wtH) {
    int e = blockIdx.x * 256 + threadIdx.x;
    if (e < N_EDGES) {
        int d = ei[N_EDGES + e];
        int p = atomicAdd(&cursor[d], 1);
        col[p] = ei[e];
    }
    if (blockIdx.x < 256) {   // wprep: 65536 elements
        int idx = blockIdx.x * 256 + threadIdx.x;
        int layer = idx >> 14;
        int rem = idx & 16383;
        int j = rem & 7;
        int lane = (rem >> 3) & 63;
        int chunk = rem >> 9;          // 0..31 = wave*8 + s*2 + ct
        int wave = chunk >> 3;
        int s = (chunk >> 1) & 3;
        int ct = chunk & 1;
        int n = wave * 32 + ct * 16 + (lane & 15);
        int k = s * 32 + (lane >> 4) * 8 + j;
        const float* W = (layer == 0) ? W1 : (layer == 1) ? W2 : (layer == 2) ? W3 : W4;
        wtH[layer * 16384 + rem] = (f16)W[k * NF + n];
    }
}

// ---------------- agg core: unweighted gather (z pre-scaled by dinv) -------
// R17 note: agg gather is at the random-access request-rate ceiling
// (~3.6 TB/s effective across R0/R1/R2 variants) — FROZEN.

__device__ __forceinline__ void agg_tail(const half8* __restrict__ z8,
                                         const int* __restrict__ col,
                                         int sbase, int fl, int beg, int end,
                                         float acc[8]) {
    // edges beyond the first 16 (deg>16, ~1e-4 of nodes)
    for (int c = beg + 16; c < end; c += 16) {
        int ce = c + fl;
        int cv = (ce < end) ? col[ce] : 0;
        int mc = end - c; if (mc > 16) mc = 16;
        for (int j = 0; j < mc; j += 4) {
            int kk = mc - j;
            half8 v0 = {}, v1 = {}, v2 = {}, v3 = {};
            int s0 = __shfl(cv, sbase + j + 0, 64);
            v0 = z8[(size_t)s0 * 16 + fl];
            if (kk > 1) { int s1 = __shfl(cv, sbase + j + 1, 64); v1 = z8[(size_t)s1 * 16 + fl]; }
            if (kk > 2) { int s2 = __shfl(cv, sbase + j + 2, 64); v2 = z8[(size_t)s2 * 16 + fl]; }
            if (kk > 3) { int s3 = __shfl(cv, sbase + j + 3, 64); v3 = z8[(size_t)s3 * 16 + fl]; }
#pragma unroll
            for (int q = 0; q < 8; q++) acc[q] += (float)v0[q];
            if (kk > 1) {
#pragma unroll
                for (int q = 0; q < 8; q++) acc[q] += (float)v1[q];
            }
            if (kk > 2) {
#pragma unroll
                for (int q = 0; q < 8; q++) acc[q] += (float)v2[q];
            }
            if (kk > 3) {
#pragma unroll
                for (int q = 0; q < 8; q++) acc[q] += (float)v3[q];
            }
        }
    }
}

__device__ __forceinline__ void agg_pair(const half8* __restrict__ z8,
                                         const int* __restrict__ col,
                                         int sbase, int fl,
                                         int begA, int endA, int begB, int endB,
                                         int colvA, int colvB,
                                         float accA[8], float accB[8]) {
    int mA = endA - begA; if (mA > 16) mA = 16;
    int mB = endB - begB; if (mB > 16) mB = 16;
    const int mmax = (mA > mB) ? mA : mB;
    for (int j = 0; j < mmax; j += 4) {
        const int kA = mA - j, kB = mB - j;
        half8 vA0 = {}, vA1 = {}, vA2 = {}, vA3 = {};
        half8 vB0 = {}, vB1 = {}, vB2 = {}, vB3 = {};
        if (kA > 0) {   // issue all A loads
            int s0 = __shfl(colvA, sbase + j + 0, 64);
            vA0 = z8[(size_t)s0 * 16 + fl];
            if (kA > 1) { int s1 = __shfl(colvA, sbase + j + 1, 64); vA1 = z8[(size_t)s1 * 16 + fl]; }
            if (kA > 2) { int s2 = __shfl(colvA, sbase + j + 2, 64); vA2 = z8[(size_t)s2 * 16 + fl]; }
            if (kA > 3) { int s3 = __shfl(colvA, sbase + j + 3, 64); vA3 = z8[(size_t)s3 * 16 + fl]; }
        }
        if (kB > 0) {   // issue all B loads before any accumulate waits
            int s0 = __shfl(colvB, sbase + j + 0, 64);
            vB0 = z8[(size_t)s0 * 16 + fl];
            if (kB > 1) { int s1 = __shfl(colvB, sbase + j + 1, 64); vB1 = z8[(size_t)s1 * 16 + fl]; }
            if (kB > 2) { int s2 = __shfl(colvB, sbase + j + 2, 64); vB2 = z8[(size_t)s2 * 16 + fl]; }
            if (kB > 3) { int s3 = __shfl(colvB, sbase + j + 3, 64); vB3 = z8[(size_t)s3 * 16 + fl]; }
        }
        if (kA > 0) {
#pragma unroll
            for (int q = 0; q < 8; q++) accA[q] += (float)vA0[q];
            if (kA > 1) {
#pragma unroll
                for (int q = 0; q < 8; q++) accA[q] += (float)vA1[q];
            }
            if (kA > 2) {
#pragma unroll
                for (int q = 0; q < 8; q++) accA[q] += (float)vA2[q];
            }
            if (kA > 3) {
#pragma unroll
                for (int q = 0; q < 8; q++) accA[q] += (float)vA3[q];
            }
        }
        if (kB > 0) {
#pragma unroll
            for (int q = 0; q < 8; q++) accB[q] += (float)vB0[q];
            if (kB > 1) {
#pragma unroll
                for (int q = 0; q < 8; q++) accB[q] += (float)vB1[q];
            }
            if (kB > 2) {
#pragma unroll
                for (int q = 0; q < 8; q++) accB[q] += (float)vB2[q];
            }
            if (kB > 3) {
#pragma unroll
                for (int q = 0; q < 8; q++) accB[q] += (float)vB3[q];
            }
        }
    }
    if (endA - begA > 16) agg_tail(z8, col, sbase, fl, begA, endA, accA);
    if (endB - begB > 16) agg_tail(z8, col, sbase, fl, begB, endB, accB);
}

// ---------------- layer-1 GEMM: Zs[M,128] = (X @ W) * dinv, fp16 MFMA ------

__global__ __launch_bounds__(256) void k_gemm1(
    const float* __restrict__ X, const f16* __restrict__ WTH,
    const float* __restrict__ dinv, f16* __restrict__ Z, int M) {
    __shared__ __align__(16) f16 As[64 * 136];   // 17408 B; reused for C out
    __shared__ float sdi[64];

    const int t = threadIdx.x;
    const int row0 = blockIdx.x * 64;
    const int wave = t >> 6;
    const int lane = t & 63;
    const int nl = lane & 15;
    const int quad = lane >> 4;

    auto bofs = [&](int s, int ct) {
        return (size_t)((((wave * 8 + s * 2 + ct) * 64) + lane) << 3);
    };

    half8 cbh[2];
    cbh[0] = *(const half8*)(WTH + bofs(0, 0));
    cbh[1] = *(const half8*)(WTH + bofs(0, 1));

    if (t < 64) sdi[t] = (row0 + t < M) ? dinv[row0 + t] : 0.f;
#pragma unroll
    for (int q = 0; q < 8; q++) {
        int lin = t + q * 256;
        int r = lin >> 5, c4 = lin & 31;
        float4 v = make_float4(0.f, 0.f, 0.f, 0.f);
        if (row0 + r < M) v = ((const float4*)(X + (size_t)(row0 + r) * NF))[c4];
        half4v hv = {(f16)v.x, (f16)v.y, (f16)v.z, (f16)v.w};
        *(half4v*)&As[r * 136 + c4 * 4] = hv;
    }
    __syncthreads();

    float4v acc[2][4];
#pragma unroll
    for (int ct = 0; ct < 2; ct++)
#pragma unroll
        for (int rt = 0; rt < 4; rt++) acc[ct][rt] = (float4v)0.f;

#pragma unroll
    for (int s = 0; s < 4; s++) {
        half8 nbh[2];
        if (s < 3) {
            nbh[0] = *(const half8*)(WTH + bofs(s + 1, 0));
            nbh[1] = *(const half8*)(WTH + bofs(s + 1, 1));
        }
        half8 fa[4];
#pragma unroll
        for (int rt = 0; rt < 4; rt++)
            fa[rt] = *(half8*)&As[(rt * 16 + nl) * 136 + s * 32 + quad * 8];
#pragma unroll
        for (int ct = 0; ct < 2; ct++)
#pragma unroll
            for (int rt = 0; rt < 4; rt++)
                acc[ct][rt] = __builtin_amdgcn_mfma_f32_16x16x32_f16(fa[rt], cbh[ct], acc[ct][rt], 0, 0, 0);
        if (s < 3) {
            cbh[0] = nbh[0]; cbh[1] = nbh[1];
        }
    }

    __syncthreads();
#pragma unroll
    for (int ct = 0; ct < 2; ct++)
#pragma unroll
        for (int rt = 0; rt < 4; rt++)
#pragma unroll
            for (int r = 0; r < 4; r++)
                As[(rt * 16 + quad * 4 + r) * 136 + wave * 32 + ct * 16 + nl] =
                    (f16)(acc[ct][rt][r] * sdi[rt * 16 + quad * 4 + r]);
    __syncthreads();
#pragma unroll
    for (int q = 0; q < 4; q++) {
        int lin = t + q * 256;
        int r = lin >> 4, c8 = lin & 15;
        if (row0 + r < M)
            *(half8*)(Z + (size_t)(row0 + r) * NF + c8 * 8) = *(half8*)&As[r * 136 + c8 * 8];
    }
}

// ---------------- fused agg(+relu) -> GEMM, prescaled in AND out -----------

#define ACHUNK 4

__global__ __launch_bounds__(256) void k_agg_gemm(
    const f16* __restrict__ z, const float* __restrict__ dinv,
    const int* __restrict__ row_ptr, const int* __restrict__ col,
    const float* __restrict__ bias,     // bias of THIS agg layer
    const f16* __restrict__ WTH,        // fragment-ordered W of NEXT gemm
    f16* __restrict__ Zout) {
    __shared__ __align__(16) f16 As[64 * 136];   // H tile, then reused for C out
    __shared__ float sdi[64];

    const int t = threadIdx.x;
    const int slot = t >> 4;
    const int fl = t & 15;
    const int sbase = (t & 48);
    const int n0 = (blockIdx.x * 16 + slot) * ACHUNK;
    const half8* z8 = (const half8*)z;

    float bb[8];
    {
        float4 b0 = ((const float4*)bias)[fl * 2];
        float4 b1 = ((const float4*)bias)[fl * 2 + 1];
        bb[0] = b0.x; bb[1] = b0.y; bb[2] = b0.z; bb[3] = b0.w;
        bb[4] = b1.x; bb[5] = b1.y; bb[6] = b1.z; bb[7] = b1.w;
    }

    // ---- prefetch prologue: all 4 nodes' metadata + self rows + col chunks
    int rp[5];
#pragma unroll
    for (int i = 0; i < 5; i++) {
        int n = n0 + i;
        rp[i] = row_ptr[(n < N_NODES) ? n : N_NODES];
    }
    float dis[4]; half8 selfv[4]; int colv0[4];
#pragma unroll
    for (int i = 0; i < 4; i++) {
        int n = n0 + i;
        bool ok = n < N_NODES;
        half8 zz = {};
        dis[i] = ok ? dinv[n] : 0.f;
        selfv[i] = ok ? z8[(size_t)n * 16 + fl] : zz;
        int ce = rp[i] + fl;
        colv0[i] = (ce < rp[i + 1]) ? col[ce] : 0;
    }
    if (fl == 0) {
#pragma unroll
        for (int i = 0; i < 4; i++) sdi[slot * ACHUNK + i] = dis[i];
    }

    // ---- agg phase: node pairs, unweighted row sums, scale at the end
#pragma unroll
    for (int p = 0; p < 2; p++) {
        const int iA = 2 * p, iB = 2 * p + 1;
        float accA[8], accB[8];
#pragma unroll
        for (int q = 0; q < 8; q++) {
            accA[q] = (float)selfv[iA][q];
            accB[q] = (float)selfv[iB][q];
        }
        agg_pair(z8, col, sbase, fl, rp[iA], rp[iA + 1], rp[iB], rp[iB + 1],
                 colv0[iA], colv0[iB], accA, accB);
        half8 oA, oB;
#pragma unroll
        for (int q = 0; q < 8; q++) {
            oA[q] = (f16)fmaxf(bb[q] + dis[iA] * accA[q], 0.f);
            oB[q] = (f16)fmaxf(bb[q] + dis[iB] * accB[q], 0.f);
        }
        *(half8*)&As[(slot * ACHUNK + iA) * 136 + fl * 8] = oA;
        *(half8*)&As[(slot * ACHUNK + iB) * 136 + fl * 8] = oB;
    }

    // ---- gemm phase: Zout tile = (As @ W) * sdi ----
    const int wave = t >> 6;
    const int lane = t & 63;
    const int nl = lane & 15;
    const int quad = lane >> 4;
    const int row0 = blockIdx.x * 64;

    auto bofs = [&](int s, int ct) {
        return (size_t)((((wave * 8 + s * 2 + ct) * 64) + lane) << 3);
    };

    half8 cbh[2];   // s=0 B fragments; load overlaps the barrier wait
    cbh[0] = *(const half8*)(WTH + bofs(0, 0));
    cbh[1] = *(const half8*)(WTH + bofs(0, 1));
    __syncthreads();

    float4v acc[2][4];
#pragma unroll
    for (int ct = 0; ct < 2; ct++)
#pragma unroll
        for (int rt = 0; rt < 4; rt++) acc[ct][rt] = (float4v)0.f;

#pragma unroll
    for (int s = 0; s < 4; s++) {
        half8 nbh[2];
        if (s < 3) {
            nbh[0] = *(const half8*)(WTH + bofs(s + 1, 0));
            nbh[1] = *(const half8*)(WTH + bofs(s + 1, 1));
        }
        half8 fa[4];
#pragma unroll
        for (int rt = 0; rt < 4; rt++)
            fa[rt] = *(half8*)&As[(rt * 16 + nl) * 136 + s * 32 + quad * 8];
#pragma unroll
        for (int ct = 0; ct < 2; ct++)
#pragma unroll
            for (int rt = 0; rt < 4; rt++)
                acc[ct][rt] = __builtin_amdgcn_mfma_f32_16x16x32_f16(fa[rt], cbh[ct], acc[ct][rt], 0, 0, 0);
        if (s < 3) {
            cbh[0] = nbh[0]; cbh[1] = nbh[1];
        }
    }

    __syncthreads();
#pragma unroll
    for (int ct = 0; ct < 2; ct++)
#pragma unroll
        for (int rt = 0; rt < 4; rt++)
#pragma unroll
            for (int r = 0; r < 4; r++)
                As[(rt * 16 + quad * 4 + r) * 136 + wave * 32 + ct * 16 + nl] =
                    (f16)(acc[ct][rt][r] * sdi[rt * 16 + quad * 4 + r]);
    __syncthreads();
#pragma unroll
    for (int q = 0; q < 4; q++) {
        int lin = t + q * 256;
        int r = lin >> 4, c8 = lin & 15;
        if (row0 + r < N_NODES)
            *(half8*)(Zout + (size_t)(row0 + r) * NF + c8 * 8) = *(half8*)&As[r * 136 + c8 * 8];
    }
}

// ---------------- R17: fused final agg + mean-pool partial sums ------------
// agg block = 64 consecutive nodes = pool2's chunk; batch[] is sorted, so
// per-slot runs of equal graph id flush as 8 fp32 atomicAdds per lane.
// Eliminates the 25 MB h write + 25 MB h re-read + one dispatch. Pool now
// sums pre-f16-rounding fp32 values (strictly closer to the reference).

__global__ __launch_bounds__(256) void k_agg_pool(
    const f16* __restrict__ z, const float* __restrict__ dinv,
    const int* __restrict__ row_ptr, const int* __restrict__ col,
    const float* __restrict__ bias, const int* __restrict__ batch,
    float* __restrict__ pooled) {
    const int t = threadIdx.x;
    const int slot = t >> 4;
    const int fl = t & 15;
    const int sbase = (t & 48);
    const int n0 = (blockIdx.x * 16 + slot) * ACHUNK;
    const half8* z8 = (const half8*)z;

    float bb[8];
    {
        float4 b0 = ((const float4*)bias)[fl * 2];
        float4 b1 = ((const float4*)bias)[fl * 2 + 1];
        bb[0] = b0.x; bb[1] = b0.y; bb[2] = b0.z; bb[3] = b0.w;
        bb[4] = b1.x; bb[5] = b1.y; bb[6] = b1.z; bb[7] = b1.w;
    }

    if (n0 >= N_NODES) return;

    int rp[5];
#pragma unroll
    for (int i = 0; i < 5; i++) {
        int n = n0 + i;
        rp[i] = row_ptr[(n < N_NODES) ? n : N_NODES];
    }
    float dis[4]; half8 selfv[4]; int colv0[4]; int gid[4];
#pragma unroll
    for (int i = 0; i < 4; i++) {
        int n = n0 + i;
        bool ok = n < N_NODES;
        half8 zz = {};
        dis[i] = ok ? dinv[n] : 0.f;
        selfv[i] = ok ? z8[(size_t)n * 16 + fl] : zz;
        int ce = rp[i] + fl;
        colv0[i] = (ce < rp[i + 1]) ? col[ce] : 0;
        gid[i] = batch[ok ? n : (N_NODES - 1)];
    }

    // running per-graph partial sum for this lane's 8 features
    float pacc[8];
#pragma unroll
    for (int q = 0; q < 8; q++) pacc[q] = 0.f;
    int curg = gid[0];

#pragma unroll
    for (int p = 0; p < 2; p++) {
        const int iA = 2 * p, iB = 2 * p + 1;
        float accA[8], accB[8];
#pragma unroll
        for (int q = 0; q < 8; q++) {
            accA[q] = (float)selfv[iA][q];
            accB[q] = (float)selfv[iB][q];
        }
        agg_pair(z8, col, sbase, fl, rp[iA], rp[iA + 1], rp[iB], rp[iB + 1],
                 colv0[iA], colv0[iB], accA, accB);
        // pool node iA
        if (n0 + iA < N_NODES) {
            if (gid[iA] != curg) {
#pragma unroll
                for (int q = 0; q < 8; q++) {
                    atomicAdd(&pooled[curg * NF + fl * 8 + q], pacc[q]);
                    pacc[q] = 0.f;
                }
                curg = gid[iA];
            }
#pragma unroll
            for (int q = 0; q < 8; q++)
                pacc[q] += fmaxf(bb[q] + dis[iA] * accA[q], 0.f);
        }
        // pool node iB
        if (n0 + iB < N_NODES) {
            if (gid[iB] != curg) {
#pragma unroll
                for (int q = 0; q < 8; q++) {
                    atomicAdd(&pooled[curg * NF + fl * 8 + q], pacc[q]);
                    pacc[q] = 0.f;
                }
                curg = gid[iB];
            }
#pragma unroll
            for (int q = 0; q < 8; q++)
                pacc[q] += fmaxf(bb[q] + dis[iB] * accB[q], 0.f);
        }
    }
#pragma unroll
    for (int q = 0; q < 8; q++)
        atomicAdd(&pooled[curg * NF + fl * 8 + q], pacc[q]);
}

// ---------------- summary MLP ----------------

__global__ void k_mlp(const float* __restrict__ pooled, const int* __restrict__ batch,
                      const float* __restrict__ Ws1, const float* __restrict__ bs1,
                      const float* __restrict__ Ws2, const float* __restrict__ bs2,
                      float* __restrict__ out) {
    __shared__ float row[NF];
    __shared__ float red[NF];
    int g = blockIdx.x, f = threadIdx.x;
    int lo = 0, hi = N_NODES;
    while (lo < hi) { int mid = (lo + hi) >> 1; if (batch[mid] < g) lo = mid + 1; else hi = mid; }
    int start = lo;
    hi = N_NODES;
    while (lo < hi) { int mid = (lo + hi) >> 1; if (batch[mid] < g + 1) lo = mid + 1; else hi = mid; }
    float cnt = (float)(lo - start);
    row[f] = pooled[g * NF + f] / fmaxf(cnt, 1.f);
    __syncthreads();
    float t = bs1[f];
    for (int k = 0; k < NF; k++) t += row[k] * Ws1[k * NF + f];
    t = fmaxf(t, 0.f);
    red[f] = t * Ws2[f];
    __syncthreads();
    for (int s = 64; s > 0; s >>= 1) {
        if (f < s) red[f] += red[f + s];
        __syncthreads();
    }
    if (f == 0) out[g] = red[0] + bs2[0];
}

// ---------------- driver ----------------

extern "C" void kernel_launch(void* const* d_in, const int* in_sizes, int n_in,
                              void* d_out, int out_size, void* d_ws, size_t ws_size,
                              hipStream_t stream) {
    const float* x    = (const float*)d_in[0];
    const int*   ei   = (const int*)d_in[1];
    const int*   batch= (const int*)d_in[2];
    const float* W1 = (const float*)d_in[3];  const float* b1 = (const float*)d_in[4];
    const float* W2 = (const float*)d_in[5];  const float* b2 = (const float*)d_in[6];
    const float* W3 = (const float*)d_in[7];  const float* b3 = (const float*)d_in[8];
    const float* W4 = (const float*)d_in[9];  const float* b4 = (const float*)d_in[10];
    const float* Ws1= (const float*)d_in[11]; const float* bs1= (const float*)d_in[12];
    const float* Ws2= (const float*)d_in[13]; const float* bs2= (const float*)d_in[14];
    float* out = (float*)d_out;

    char* ws = (char*)d_ws;
    size_t off = 0;
    auto alloc = [&](size_t bytes) {
        void* p = ws + off;
        off += (bytes + 255) & ~(size_t)255;
        return p;
    };
    f16*   bufA   = (f16*)alloc((size_t)N_NODES * NF * 2);
    f16*   bufB   = (f16*)alloc((size_t)N_NODES * NF * 2);
    f16*   wtH    = (f16*)alloc((size_t)4 * NF * NF * 2);
    int*   counts = (int*)alloc((size_t)N_NODES * 4);
    int*   row_ptr= (int*)alloc((size_t)(N_NODES + 1) * 4);
    int*   cursor = (int*)alloc((size_t)N_NODES * 4);
    int*   col    = (int*)alloc((size_t)N_EDGES * 4);
    int*   bsums  = (int*)alloc(64 * 4);
    float* dinv   = (float*)alloc((size_t)N_NODES * 4);
    float* pooled = (float*)alloc((size_t)NG * NF * 4);

    hipMemsetAsync(counts, 0, (size_t)N_NODES * 4, stream);
    hipMemsetAsync(pooled, 0, (size_t)NG * NF * 4, stream);
    k_count<<<(N_EDGES + 255) / 256, 256, 0, stream>>>(ei, counts);
    int nscan = (N_NODES + 2047) / 2048;  // 49
    k_scan1<<<nscan, 256, 0, stream>>>(counts, row_ptr, bsums, dinv);
    k_scan3<<<(N_NODES + 255) / 256, 256, 0, stream>>>(row_ptr, bsums, cursor);
    k_fill<<<(N_EDGES + 255) / 256, 256, 0, stream>>>(ei, cursor, col,
                                                      W1, W2, W3, W4, wtH);

    int gblocks = (N_NODES + 63) / 64;                          // 1563
    int ablocks = (N_NODES + 16 * ACHUNK - 1) / (16 * ACHUNK);  // 1563

    // layer 1 gemm: Zs0 = (X @ W1) * dinv
    k_gemm1<<<gblocks, 256, 0, stream>>>(x, wtH, dinv, bufA, N_NODES);
    // fused interior boundaries: agg(l)+relu -> (@W(l+1)) * dinv
    k_agg_gemm<<<gblocks, 256, 0, stream>>>(bufA, dinv, row_ptr, col, b1,
                                            wtH + 16384, bufB);   // Zs1
    k_agg_gemm<<<gblocks, 256, 0, stream>>>(bufB, dinv, row_ptr, col, b2,
                                            wtH + 32768, bufA);   // Zs2
    k_agg_gemm<<<gblocks, 256, 0, stream>>>(bufA, dinv, row_ptr, col, b3,
                                            wtH + 49152, bufB);   // Zs3
    // final agg fused with mean-pool partial sums (no h materialization)
    k_agg_pool<<<ablocks, 256, 0, stream>>>(bufB, dinv, row_ptr, col, b4,
                                            batch, pooled);
    k_mlp<<<NG, 128, 0, stream>>>(pooled, batch, Ws1, bs1, Ws2, bs2, out);
}

// Round 4
// 361.142 us; speedup vs baseline: 1.2882x; 1.2882x over previous
//
#include <hip/hip_runtime.h>

#define N_NODES 100000
#define N_EDGES 600000
#define NF 128
#define NG 256

typedef _Float16 f16;
typedef f16 half8 __attribute__((ext_vector_type(8)));
typedef f16 half4v __attribute__((ext_vector_type(4)));
typedef float float4v __attribute__((ext_vector_type(4)));

// ---------------- preprocessing: degrees, dinv, CSR ----------------

__global__ void k_count(const int* __restrict__ ei, int* __restrict__ counts) {
    int e = blockIdx.x * 256 + threadIdx.x;
    if (e < N_EDGES) atomicAdd(&counts[ei[N_EDGES + e]], 1);
}

__global__ void k_scan1(const int* __restrict__ counts, int* __restrict__ row_ptr,
                        int* __restrict__ bsums, float* __restrict__ dinv) {
    __shared__ int s[256];
    int b = blockIdx.x, t = threadIdx.x;
    int base = b * 2048 + t * 8;
    int local[8];
    int sum = 0;
#pragma unroll
    for (int q = 0; q < 8; q++) {
        int idx = base + q;
        int v = (idx < N_NODES) ? counts[idx] : 0;
        if (idx < N_NODES) dinv[idx] = 1.0f / sqrtf((float)(v + 1));
        local[q] = sum;
        sum += v;
    }
    s[t] = sum;
    __syncthreads();
    for (int off = 1; off < 256; off <<= 1) {
        int v = 0;
        if (t >= off) v = s[t - off];
        __syncthreads();
        s[t] += v;
        __syncthreads();
    }
    int excl = s[t] - sum;
#pragma unroll
    for (int q = 0; q < 8; q++) {
        int idx = base + q;
        if (idx < N_NODES) row_ptr[idx] = excl + local[q];
    }
    if (t == 255) bsums[b] = s[255];   // raw per-block sums (prefixed in scan3)
}

// scan3 folds the bsums prefix (2048-node group per 8 blocks of 256)
__global__ void k_scan3(int* __restrict__ row_ptr, const int* __restrict__ bsums,
                        int* __restrict__ cursor) {
    __shared__ int pre;
    if (threadIdx.x == 0) {
        int g = blockIdx.x >> 3;
        int s = 0;
        for (int j = 0; j < g; j++) s += bsums[j];
        pre = s;
    }
    __syncthreads();
    int i = blockIdx.x * 256 + threadIdx.x;
    if (i < N_NODES) {
        int v = row_ptr[i] + pre;
        row_ptr[i] = v;
        cursor[i] = v;
        if (i == 0) row_ptr[N_NODES] = N_EDGES;
    }
}

// fill CSR col[]; first 256 blocks also do wprep in FRAGMENT ORDER (R11-proven).
__global__ void k_fill(const int* __restrict__ ei, int* __restrict__ cursor,
                       int* __restrict__ col,
                       const float* __restrict__ W1, const float* __restrict__ W2,
                       const float* __restrict__ W3, const float* __restrict__ W4,
                       f16* __restrict__ wtH) {
    int e = blockIdx.x * 256 + threadIdx.x;
    if (e < N_EDGES) {
        int d = ei[N_EDGES + e];
        int p = atomicAdd(&cursor[d], 1);
        col[p] = ei[e];
    }
    if (blockIdx.x < 256) {   // wprep: 65536 elements
        int idx = blockIdx.x * 256 + threadIdx.x;
        int layer = idx >> 14;
        int rem = idx & 16383;
        int j = rem & 7;
        int lane = (rem >> 3) & 63;
        int chunk = rem >> 9;          // 0..31 = wave*8 + s*2 + ct
        int wave = chunk >> 3;
        int s = (chunk >> 1) & 3;
        int ct = chunk & 1;
        int n = wave * 32 + ct * 16 + (lane & 15);
        int k = s * 32 + (lane >> 4) * 8 + j;
        const float* W = (layer == 0) ? W1 : (layer == 1) ? W2 : (layer == 2) ? W3 : W4;
        wtH[layer * 16384 + rem] = (f16)W[k * NF + n];
    }
}

// ---------------- agg core: unweighted gather (z pre-scaled by dinv) -------
// R17 note: agg gather is at the random-access request-rate ceiling
// (~3.6 TB/s effective across R0/R1/R2 variants) — FROZEN.

__device__ __forceinline__ void agg_tail(const half8* __restrict__ z8,
                                         const int* __restrict__ col,
                                         int sbase, int fl, int beg, int end,
                                         float acc[8]) {
    // edges beyond the first 16 (deg>16, ~1e-4 of nodes)
    for (int c = beg + 16; c < end; c += 16) {
        int ce = c + fl;
        int cv = (ce < end) ? col[ce] : 0;
        int mc = end - c; if (mc > 16) mc = 16;
        for (int j = 0; j < mc; j += 4) {
            int kk = mc - j;
            half8 v0 = {}, v1 = {}, v2 = {}, v3 = {};
            int s0 = __shfl(cv, sbase + j + 0, 64);
            v0 = z8[(size_t)s0 * 16 + fl];
            if (kk > 1) { int s1 = __shfl(cv, sbase + j + 1, 64); v1 = z8[(size_t)s1 * 16 + fl]; }
            if (kk > 2) { int s2 = __shfl(cv, sbase + j + 2, 64); v2 = z8[(size_t)s2 * 16 + fl]; }
            if (kk > 3) { int s3 = __shfl(cv, sbase + j + 3, 64); v3 = z8[(size_t)s3 * 16 + fl]; }
#pragma unroll
            for (int q = 0; q < 8; q++) acc[q] += (float)v0[q];
            if (kk > 1) {
#pragma unroll
                for (int q = 0; q < 8; q++) acc[q] += (float)v1[q];
            }
            if (kk > 2) {
#pragma unroll
                for (int q = 0; q < 8; q++) acc[q] += (float)v2[q];
            }
            if (kk > 3) {
#pragma unroll
                for (int q = 0; q < 8; q++) acc[q] += (float)v3[q];
            }
        }
    }
}

__device__ __forceinline__ void agg_pair(const half8* __restrict__ z8,
                                         const int* __restrict__ col,
                                         int sbase, int fl,
                                         int begA, int endA, int begB, int endB,
                                         int colvA, int colvB,
                                         float accA[8], float accB[8]) {
    int mA = endA - begA; if (mA > 16) mA = 16;
    int mB = endB - begB; if (mB > 16) mB = 16;
    const int mmax = (mA > mB) ? mA : mB;
    for (int j = 0; j < mmax; j += 4) {
        const int kA = mA - j, kB = mB - j;
        half8 vA0 = {}, vA1 = {}, vA2 = {}, vA3 = {};
        half8 vB0 = {}, vB1 = {}, vB2 = {}, vB3 = {};
        if (kA > 0) {   // issue all A loads
            int s0 = __shfl(colvA, sbase + j + 0, 64);
            vA0 = z8[(size_t)s0 * 16 + fl];
            if (kA > 1) { int s1 = __shfl(colvA, sbase + j + 1, 64); vA1 = z8[(size_t)s1 * 16 + fl]; }
            if (kA > 2) { int s2 = __shfl(colvA, sbase + j + 2, 64); vA2 = z8[(size_t)s2 * 16 + fl]; }
            if (kA > 3) { int s3 = __shfl(colvA, sbase + j + 3, 64); vA3 = z8[(size_t)s3 * 16 + fl]; }
        }
        if (kB > 0) {   // issue all B loads before any accumulate waits
            int s0 = __shfl(colvB, sbase + j + 0, 64);
            vB0 = z8[(size_t)s0 * 16 + fl];
            if (kB > 1) { int s1 = __shfl(colvB, sbase + j + 1, 64); vB1 = z8[(size_t)s1 * 16 + fl]; }
            if (kB > 2) { int s2 = __shfl(colvB, sbase + j + 2, 64); vB2 = z8[(size_t)s2 * 16 + fl]; }
            if (kB > 3) { int s3 = __shfl(colvB, sbase + j + 3, 64); vB3 = z8[(size_t)s3 * 16 + fl]; }
        }
        if (kA > 0) {
#pragma unroll
            for (int q = 0; q < 8; q++) accA[q] += (float)vA0[q];
            if (kA > 1) {
#pragma unroll
                for (int q = 0; q < 8; q++) accA[q] += (float)vA1[q];
            }
            if (kA > 2) {
#pragma unroll
                for (int q = 0; q < 8; q++) accA[q] += (float)vA2[q];
            }
            if (kA > 3) {
#pragma unroll
                for (int q = 0; q < 8; q++) accA[q] += (float)vA3[q];
            }
        }
        if (kB > 0) {
#pragma unroll
            for (int q = 0; q < 8; q++) accB[q] += (float)vB0[q];
            if (kB > 1) {
#pragma unroll
                for (int q = 0; q < 8; q++) accB[q] += (float)vB1[q];
            }
            if (kB > 2) {
#pragma unroll
                for (int q = 0; q < 8; q++) accB[q] += (float)vB2[q];
            }
            if (kB > 3) {
#pragma unroll
                for (int q = 0; q < 8; q++) accB[q] += (float)vB3[q];
            }
        }
    }
    if (endA - begA > 16) agg_tail(z8, col, sbase, fl, begA, endA, accA);
    if (endB - begB > 16) agg_tail(z8, col, sbase, fl, begB, endB, accB);
}

// ---------------- layer-1 GEMM: Zs[M,128] = (X @ W) * dinv, fp16 MFMA ------

__global__ __launch_bounds__(256) void k_gemm1(
    const float* __restrict__ X, const f16* __restrict__ WTH,
    const float* __restrict__ dinv, f16* __restrict__ Z, int M) {
    __shared__ __align__(16) f16 As[64 * 136];   // 17408 B; reused for C out
    __shared__ float sdi[64];

    const int t = threadIdx.x;
    const int row0 = blockIdx.x * 64;
    const int wave = t >> 6;
    const int lane = t & 63;
    const int nl = lane & 15;
    const int quad = lane >> 4;

    auto bofs = [&](int s, int ct) {
        return (size_t)((((wave * 8 + s * 2 + ct) * 64) + lane) << 3);
    };

    half8 cbh[2];
    cbh[0] = *(const half8*)(WTH + bofs(0, 0));
    cbh[1] = *(const half8*)(WTH + bofs(0, 1));

    if (t < 64) sdi[t] = (row0 + t < M) ? dinv[row0 + t] : 0.f;
#pragma unroll
    for (int q = 0; q < 8; q++) {
        int lin = t + q * 256;
        int r = lin >> 5, c4 = lin & 31;
        float4 v = make_float4(0.f, 0.f, 0.f, 0.f);
        if (row0 + r < M) v = ((const float4*)(X + (size_t)(row0 + r) * NF))[c4];
        half4v hv = {(f16)v.x, (f16)v.y, (f16)v.z, (f16)v.w};
        *(half4v*)&As[r * 136 + c4 * 4] = hv;
    }
    __syncthreads();

    float4v acc[2][4];
#pragma unroll
    for (int ct = 0; ct < 2; ct++)
#pragma unroll
        for (int rt = 0; rt < 4; rt++) acc[ct][rt] = (float4v)0.f;

#pragma unroll
    for (int s = 0; s < 4; s++) {
        half8 nbh[2];
        if (s < 3) {
            nbh[0] = *(const half8*)(WTH + bofs(s + 1, 0));
            nbh[1] = *(const half8*)(WTH + bofs(s + 1, 1));
        }
        half8 fa[4];
#pragma unroll
        for (int rt = 0; rt < 4; rt++)
            fa[rt] = *(half8*)&As[(rt * 16 + nl) * 136 + s * 32 + quad * 8];
#pragma unroll
        for (int ct = 0; ct < 2; ct++)
#pragma unroll
            for (int rt = 0; rt < 4; rt++)
                acc[ct][rt] = __builtin_amdgcn_mfma_f32_16x16x32_f16(fa[rt], cbh[ct], acc[ct][rt], 0, 0, 0);
        if (s < 3) {
            cbh[0] = nbh[0]; cbh[1] = nbh[1];
        }
    }

    __syncthreads();
#pragma unroll
    for (int ct = 0; ct < 2; ct++)
#pragma unroll
        for (int rt = 0; rt < 4; rt++)
#pragma unroll
            for (int r = 0; r < 4; r++)
                As[(rt * 16 + quad * 4 + r) * 136 + wave * 32 + ct * 16 + nl] =
                    (f16)(acc[ct][rt][r] * sdi[rt * 16 + quad * 4 + r]);
    __syncthreads();
#pragma unroll
    for (int q = 0; q < 4; q++) {
        int lin = t + q * 256;
        int r = lin >> 4, c8 = lin & 15;
        if (row0 + r < M)
            *(half8*)(Z + (size_t)(row0 + r) * NF + c8 * 8) = *(half8*)&As[r * 136 + c8 * 8];
    }
}

// ---------------- fused agg(+relu) -> GEMM, prescaled in AND out -----------

#define ACHUNK 4

__global__ __launch_bounds__(256) void k_agg_gemm(
    const f16* __restrict__ z, const float* __restrict__ dinv,
    const int* __restrict__ row_ptr, const int* __restrict__ col,
    const float* __restrict__ bias,     // bias of THIS agg layer
    const f16* __restrict__ WTH,        // fragment-ordered W of NEXT gemm
    f16* __restrict__ Zout) {
    __shared__ __align__(16) f16 As[64 * 136];   // H tile, then reused for C out
    __shared__ float sdi[64];

    const int t = threadIdx.x;
    const int slot = t >> 4;
    const int fl = t & 15;
    const int sbase = (t & 48);
    const int n0 = (blockIdx.x * 16 + slot) * ACHUNK;
    const half8* z8 = (const half8*)z;

    float bb[8];
    {
        float4 b0 = ((const float4*)bias)[fl * 2];
        float4 b1 = ((const float4*)bias)[fl * 2 + 1];
        bb[0] = b0.x; bb[1] = b0.y; bb[2] = b0.z; bb[3] = b0.w;
        bb[4] = b1.x; bb[5] = b1.y; bb[6] = b1.z; bb[7] = b1.w;
    }

    // ---- prefetch prologue: all 4 nodes' metadata + self rows + col chunks
    int rp[5];
#pragma unroll
    for (int i = 0; i < 5; i++) {
        int n = n0 + i;
        rp[i] = row_ptr[(n < N_NODES) ? n : N_NODES];
    }
    float dis[4]; half8 selfv[4]; int colv0[4];
#pragma unroll
    for (int i = 0; i < 4; i++) {
        int n = n0 + i;
        bool ok = n < N_NODES;
        half8 zz = {};
        dis[i] = ok ? dinv[n] : 0.f;
        selfv[i] = ok ? z8[(size_t)n * 16 + fl] : zz;
        int ce = rp[i] + fl;
        colv0[i] = (ce < rp[i + 1]) ? col[ce] : 0;
    }
    if (fl == 0) {
#pragma unroll
        for (int i = 0; i < 4; i++) sdi[slot * ACHUNK + i] = dis[i];
    }

    // ---- agg phase: node pairs, unweighted row sums, scale at the end
#pragma unroll
    for (int p = 0; p < 2; p++) {
        const int iA = 2 * p, iB = 2 * p + 1;
        float accA[8], accB[8];
#pragma unroll
        for (int q = 0; q < 8; q++) {
            accA[q] = (float)selfv[iA][q];
            accB[q] = (float)selfv[iB][q];
        }
        agg_pair(z8, col, sbase, fl, rp[iA], rp[iA + 1], rp[iB], rp[iB + 1],
                 colv0[iA], colv0[iB], accA, accB);
        half8 oA, oB;
#pragma unroll
        for (int q = 0; q < 8; q++) {
            oA[q] = (f16)fmaxf(bb[q] + dis[iA] * accA[q], 0.f);
            oB[q] = (f16)fmaxf(bb[q] + dis[iB] * accB[q], 0.f);
        }
        *(half8*)&As[(slot * ACHUNK + iA) * 136 + fl * 8] = oA;
        *(half8*)&As[(slot * ACHUNK + iB) * 136 + fl * 8] = oB;
    }

    // ---- gemm phase: Zout tile = (As @ W) * sdi ----
    const int wave = t >> 6;
    const int lane = t & 63;
    const int nl = lane & 15;
    const int quad = lane >> 4;
    const int row0 = blockIdx.x * 64;

    auto bofs = [&](int s, int ct) {
        return (size_t)((((wave * 8 + s * 2 + ct) * 64) + lane) << 3);
    };

    half8 cbh[2];   // s=0 B fragments; load overlaps the barrier wait
    cbh[0] = *(const half8*)(WTH + bofs(0, 0));
    cbh[1] = *(const half8*)(WTH + bofs(0, 1));
    __syncthreads();

    float4v acc[2][4];
#pragma unroll
    for (int ct = 0; ct < 2; ct++)
#pragma unroll
        for (int rt = 0; rt < 4; rt++) acc[ct][rt] = (float4v)0.f;

#pragma unroll
    for (int s = 0; s < 4; s++) {
        half8 nbh[2];
        if (s < 3) {
            nbh[0] = *(const half8*)(WTH + bofs(s + 1, 0));
            nbh[1] = *(const half8*)(WTH + bofs(s + 1, 1));
        }
        half8 fa[4];
#pragma unroll
        for (int rt = 0; rt < 4; rt++)
            fa[rt] = *(half8*)&As[(rt * 16 + nl) * 136 + s * 32 + quad * 8];
#pragma unroll
        for (int ct = 0; ct < 2; ct++)
#pragma unroll
            for (int rt = 0; rt < 4; rt++)
                acc[ct][rt] = __builtin_amdgcn_mfma_f32_16x16x32_f16(fa[rt], cbh[ct], acc[ct][rt], 0, 0, 0);
        if (s < 3) {
            cbh[0] = nbh[0]; cbh[1] = nbh[1];
        }
    }

    __syncthreads();
#pragma unroll
    for (int ct = 0; ct < 2; ct++)
#pragma unroll
        for (int rt = 0; rt < 4; rt++)
#pragma unroll
            for (int r = 0; r < 4; r++)
                As[(rt * 16 + quad * 4 + r) * 136 + wave * 32 + ct * 16 + nl] =
                    (f16)(acc[ct][rt][r] * sdi[rt * 16 + quad * 4 + r]);
    __syncthreads();
#pragma unroll
    for (int q = 0; q < 4; q++) {
        int lin = t + q * 256;
        int r = lin >> 4, c8 = lin & 15;
        if (row0 + r < N_NODES)
            *(half8*)(Zout + (size_t)(row0 + r) * NF + c8 * 8) = *(half8*)&As[r * 136 + c8 * 8];
    }
}

// ---------------- R18: fused final agg + mean-pool via LDS -----------------
// R17's per-slot atomic flush was the regression (3.2M scalar atomics).
// Fix: dump fp32 relu'd rows into a [64][132] LDS tile (pad +4 breaks the
// write-phase bank aliasing), one barrier, then 128 threads scan the 64
// sorted rows flushing one atomicAdd per (graph-run, feature) — same atomic
// count as the old k_pool2 (~230K total) but without the 25 MB h write and
// 25 MB h re-read.

#define HP 132   // padded row stride (floats)

__global__ __launch_bounds__(256) void k_agg_pool(
    const f16* __restrict__ z, const float* __restrict__ dinv,
    const int* __restrict__ row_ptr, const int* __restrict__ col,
    const float* __restrict__ bias, const int* __restrict__ batch,
    float* __restrict__ pooled) {
    __shared__ float hs[64 * HP];   // 33792 B
    __shared__ int gids[64];

    const int t = threadIdx.x;
    const int slot = t >> 4;
    const int fl = t & 15;
    const int sbase = (t & 48);
    const int n0 = (blockIdx.x * 16 + slot) * ACHUNK;
    const int base_node = blockIdx.x * 64;
    const half8* z8 = (const half8*)z;

    float bb[8];
    {
        float4 b0 = ((const float4*)bias)[fl * 2];
        float4 b1 = ((const float4*)bias)[fl * 2 + 1];
        bb[0] = b0.x; bb[1] = b0.y; bb[2] = b0.z; bb[3] = b0.w;
        bb[4] = b1.x; bb[5] = b1.y; bb[6] = b1.z; bb[7] = b1.w;
    }

    if (t < 64) {
        int n = base_node + t;
        gids[t] = (n < N_NODES) ? batch[n] : -1;
    }

    int rp[5];
#pragma unroll
    for (int i = 0; i < 5; i++) {
        int n = n0 + i;
        rp[i] = row_ptr[(n < N_NODES) ? n : N_NODES];
    }
    float dis[4]; half8 selfv[4]; int colv0[4];
#pragma unroll
    for (int i = 0; i < 4; i++) {
        int n = n0 + i;
        bool ok = n < N_NODES;
        half8 zz = {};
        dis[i] = ok ? dinv[n] : 0.f;
        selfv[i] = ok ? z8[(size_t)n * 16 + fl] : zz;
        int ce = rp[i] + fl;
        colv0[i] = (ce < rp[i + 1]) ? col[ce] : 0;
    }

#pragma unroll
    for (int p = 0; p < 2; p++) {
        const int iA = 2 * p, iB = 2 * p + 1;
        float accA[8], accB[8];
#pragma unroll
        for (int q = 0; q < 8; q++) {
            accA[q] = (float)selfv[iA][q];
            accB[q] = (float)selfv[iB][q];
        }
        agg_pair(z8, col, sbase, fl, rp[iA], rp[iA + 1], rp[iB], rp[iB + 1],
                 colv0[iA], colv0[iB], accA, accB);
        float4v a0, a1, b0v, b1v;
#pragma unroll
        for (int q = 0; q < 4; q++) {
            a0[q]  = fmaxf(bb[q]     + dis[iA] * accA[q],     0.f);
            a1[q]  = fmaxf(bb[q + 4] + dis[iA] * accA[q + 4], 0.f);
            b0v[q] = fmaxf(bb[q]     + dis[iB] * accB[q],     0.f);
            b1v[q] = fmaxf(bb[q + 4] + dis[iB] * accB[q + 4], 0.f);
        }
        *(float4v*)&hs[(slot * ACHUNK + iA) * HP + fl * 8]     = a0;
        *(float4v*)&hs[(slot * ACHUNK + iA) * HP + fl * 8 + 4] = a1;
        *(float4v*)&hs[(slot * ACHUNK + iB) * HP + fl * 8]     = b0v;
        *(float4v*)&hs[(slot * ACHUNK + iB) * HP + fl * 8 + 4] = b1v;
    }
    __syncthreads();

    // ---- pool scan: thread t<128 owns feature t; rows sorted by graph ----
    if (t < NF) {
        float acc = 0.f;
        int curg = -1;
        for (int r = 0; r < 64; r++) {
            int g = gids[r];
            if (g < 0) break;              // padding rows are trailing
            if (g != curg) {
                if (curg >= 0) atomicAdd(&pooled[curg * NF + t], acc);
                acc = 0.f;
                curg = g;
            }
            acc += hs[r * HP + t];
        }
        if (curg >= 0) atomicAdd(&pooled[curg * NF + t], acc);
    }
}

// ---------------- summary MLP ----------------

__global__ void k_mlp(const float* __restrict__ pooled, const int* __restrict__ batch,
                      const float* __restrict__ Ws1, const float* __restrict__ bs1,
                      const float* __restrict__ Ws2, const float* __restrict__ bs2,
                      float* __restrict__ out) {
    __shared__ float row[NF];
    __shared__ float red[NF];
    int g = blockIdx.x, f = threadIdx.x;
    int lo = 0, hi = N_NODES;
    while (lo < hi) { int mid = (lo + hi) >> 1; if (batch[mid] < g) lo = mid + 1; else hi = mid; }
    int start = lo;
    hi = N_NODES;
    while (lo < hi) { int mid = (lo + hi) >> 1; if (batch[mid] < g + 1) lo = mid + 1; else hi = mid; }
    float cnt = (float)(lo - start);
    row[f] = pooled[g * NF + f] / fmaxf(cnt, 1.f);
    __syncthreads();
    float t = bs1[f];
    for (int k = 0; k < NF; k++) t += row[k] * Ws1[k * NF + f];
    t = fmaxf(t, 0.f);
    red[f] = t * Ws2[f];
    __syncthreads();
    for (int s = 64; s > 0; s >>= 1) {
        if (f < s) red[f] += red[f + s];
        __syncthreads();
    }
    if (f == 0) out[g] = red[0] + bs2[0];
}

// ---------------- driver ----------------

extern "C" void kernel_launch(void* const* d_in, const int* in_sizes, int n_in,
                              void* d_out, int out_size, void* d_ws, size_t ws_size,
                              hipStream_t stream) {
    const float* x    = (const float*)d_in[0];
    const int*   ei   = (const int*)d_in[1];
    const int*   batch= (const int*)d_in[2];
    const float* W1 = (const float*)d_in[3];  const float* b1 = (const float*)d_in[4];
    const float* W2 = (const float*)d_in[5];  const float* b2 = (const float*)d_in[6];
    const float* W3 = (const float*)d_in[7];  const float* b3 = (const float*)d_in[8];
    const float* W4 = (const float*)d_in[9];  const float* b4 = (const float*)d_in[10];
    const float* Ws1= (const float*)d_in[11]; const float* bs1= (const float*)d_in[12];
    const float* Ws2= (const float*)d_in[13]; const float* bs2= (const float*)d_in[14];
    float* out = (float*)d_out;

    char* ws = (char*)d_ws;
    size_t off = 0;
    auto alloc = [&](size_t bytes) {
        void* p = ws + off;
        off += (bytes + 255) & ~(size_t)255;
        return p;
    };
    f16*   bufA   = (f16*)alloc((size_t)N_NODES * NF * 2);
    f16*   bufB   = (f16*)alloc((size_t)N_NODES * NF * 2);
    f16*   wtH    = (f16*)alloc((size_t)4 * NF * NF * 2);
    int*   counts = (int*)alloc((size_t)N_NODES * 4);
    int*   row_ptr= (int*)alloc((size_t)(N_NODES + 1) * 4);
    int*   cursor = (int*)alloc((size_t)N_NODES * 4);
    int*   col    = (int*)alloc((size_t)N_EDGES * 4);
    int*   bsums  = (int*)alloc(64 * 4);
    float* dinv   = (float*)alloc((size_t)N_NODES * 4);
    float* pooled = (float*)alloc((size_t)NG * NF * 4);

    hipMemsetAsync(counts, 0, (size_t)N_NODES * 4, stream);
    hipMemsetAsync(pooled, 0, (size_t)NG * NF * 4, stream);
    k_count<<<(N_EDGES + 255) / 256, 256, 0, stream>>>(ei, counts);
    int nscan = (N_NODES + 2047) / 2048;  // 49
    k_scan1<<<nscan, 256, 0, stream>>>(counts, row_ptr, bsums, dinv);
    k_scan3<<<(N_NODES + 255) / 256, 256, 0, stream>>>(row_ptr, bsums, cursor);
    k_fill<<<(N_EDGES + 255) / 256, 256, 0, stream>>>(ei, cursor, col,
                                                      W1, W2, W3, W4, wtH);

    int gblocks = (N_NODES + 63) / 64;                          // 1563

    // layer 1 gemm: Zs0 = (X @ W1) * dinv
    k_gemm1<<<gblocks, 256, 0, stream>>>(x, wtH, dinv, bufA, N_NODES);
    // fused interior boundaries: agg(l)+relu -> (@W(l+1)) * dinv
    k_agg_gemm<<<gblocks, 256, 0, stream>>>(bufA, dinv, row_ptr, col, b1,
                                            wtH + 16384, bufB);   // Zs1
    k_agg_gemm<<<gblocks, 256, 0, stream>>>(bufB, dinv, row_ptr, col, b2,
                                            wtH + 32768, bufA);   // Zs2
    k_agg_gemm<<<gblocks, 256, 0, stream>>>(bufA, dinv, row_ptr, col, b3,
                                            wtH + 49152, bufB);   // Zs3
    // final agg fused with LDS mean-pool partial sums (no h materialization)
    k_agg_pool<<<gblocks, 256, 0, stream>>>(bufB, dinv, row_ptr, col, b4,
                                            batch, pooled);
    k_mlp<<<NG, 128, 0, stream>>>(pooled, batch, Ws1, bs1, Ws2, bs2, out);
}